// Round 18
// baseline (481.150 us; speedup 1.0000x reference)
//
#include <hip/hip_runtime.h>
#include <hip/hip_cooperative_groups.h>
#include <math.h>

namespace cg = cooperative_groups;

#define NN 50000
#define NE 800000
#define DF 128
#define NC 16
#define WLD 136            // padded LDS row stride (bf16 elems)
#define NBIN 391           // buckets: bin = dst>>7 (128 nodes per bucket)
#define EPB 8192           // edges per hist/scatter block
#define HB ((NE + EPB - 1) / EPB)      // 98 hist/scatter vblocks
#define GB ((NN + 63) / 64)            // 782 gemm1 vblocks
#define NAGG ((NN + 3) / 4)            // 12500 agg vblocks

typedef __bf16 bf16x8 __attribute__((ext_vector_type(8)));
typedef __bf16 bf16x4 __attribute__((ext_vector_type(4)));
typedef __bf16 bf16x2 __attribute__((ext_vector_type(2)));
typedef float  f32x4  __attribute__((ext_vector_type(4)));
typedef float  f32x2  __attribute__((ext_vector_type(2)));

struct BSMem { int sA[512]; int sB[512]; int tot[NBIN]; };
struct RKMem { int cnt[128]; int s[256]; int cur[128]; };
union MegaSMem {
    __bf16 wlds[DF * WLD];   // 34816 B
    int cur[NBIN];
    BSMem bs;
    RKMem rk;
};

// ================= shared device bodies =================

__device__ __forceinline__ void gemm1_body(int vb, const float* __restrict__ X,
                                           const float* __restrict__ W1,
                                           unsigned char* __restrict__ H1,
                                           __bf16* wlds) {
    const int t = threadIdx.x;
    const int wid = t >> 6, lane = t & 63;
    const int m0 = vb * 64 + wid * 16;
    const int m = m0 + (lane & 15);
    const int mc = (m < NN) ? m : NN - 1;
    const int l15 = lane & 15;
    const int kb = (lane >> 4) * 8;

    float4 xf[8];
#pragma unroll
    for (int q = 0; q < 4; ++q) {
        xf[2 * q]     = *(const float4*)&X[(size_t)mc * DF + q * 32 + kb];
        xf[2 * q + 1] = *(const float4*)&X[(size_t)mc * DF + q * 32 + kb + 4];
    }
    for (int i = t; i < DF * DF; i += 256) {
        int k = i >> 7, n = i & 127;
        wlds[n * WLD + k] = (__bf16)W1[i];
    }
    __syncthreads();

    f32x4 acc[8];
#pragma unroll
    for (int nf = 0; nf < 8; ++nf) acc[nf] = (f32x4){0.f, 0.f, 0.f, 0.f};
#pragma unroll
    for (int ks = 0; ks < 4; ++ks) {
        float4 x0 = xf[2 * ks], x1 = xf[2 * ks + 1];
        bf16x8 xa;
        xa[0] = (__bf16)x0.x; xa[1] = (__bf16)x0.y; xa[2] = (__bf16)x0.z; xa[3] = (__bf16)x0.w;
        xa[4] = (__bf16)x1.x; xa[5] = (__bf16)x1.y; xa[6] = (__bf16)x1.z; xa[7] = (__bf16)x1.w;
#pragma unroll
        for (int nf = 0; nf < 8; ++nf) {
            bf16x8 wa = *(const bf16x8*)&wlds[(nf * 16 + l15) * WLD + ks * 32 + kb];
            acc[nf] = __builtin_amdgcn_mfma_f32_16x16x32_bf16(wa, xa, acc[nf], 0, 0, 0);
        }
    }
    if (m < NN) {
#pragma unroll
        for (int nf = 0; nf < 8; ++nf) {   // pack 4 f32 -> 4 fp8 e4m3 bytes
            int pw = __builtin_amdgcn_cvt_pk_fp8_f32(acc[nf][0], acc[nf][1], 0, false);
            pw = __builtin_amdgcn_cvt_pk_fp8_f32(acc[nf][2], acc[nf][3], pw, true);
            *(unsigned int*)&H1[(size_t)m * DF + nf * 16 + (lane >> 4) * 4] = (unsigned int)pw;
        }
    }
}

__device__ __forceinline__ void hist_body(int bb, const int* __restrict__ dst,
                                          int* __restrict__ h, int* cur) {
    const int t = threadIdx.x;
    for (int i = t; i < NBIN; i += 256) cur[i] = 0;
    __syncthreads();
    const int base = bb * EPB;
#pragma unroll
    for (int i = 0; i < EPB / 256; ++i) {
        int e = base + i * 256 + t;
        if (e < NE) atomicAdd(&cur[dst[e] >> 7], 1);
    }
    __syncthreads();
    for (int i = t; i < NBIN; i += 256) h[i * HB + bb] = cur[i];   // bin-major
}

__device__ __forceinline__ void binscan_body(const int* __restrict__ h,
                                             int* __restrict__ binscan,
                                             int* __restrict__ gcur,
                                             const float* __restrict__ W2,
                                             __bf16* __restrict__ W2T,
                                             BSMem* bs) {
    const int t = threadIdx.x;
    for (int i = t; i < NBIN; i += 256) {
        const int* hp = h + i * HB;
        int tot = 0;
        for (int b = 0; b < HB; ++b) tot += hp[b];
        bs->tot[i] = tot;
    }
    for (int i = t; i < NC * DF; i += 256) {
        int n = i >> 7, k = i & 127;
        W2T[i] = (__bf16)W2[k * NC + n];
    }
    __syncthreads();
    int* sp = bs->sA;
    int* dp = bs->sB;
    sp[t]       = (t < NBIN) ? bs->tot[t] : 0;
    sp[t + 256] = (t + 256 < NBIN) ? bs->tot[t + 256] : 0;
    __syncthreads();
    for (int o = 1; o < 512; o <<= 1) {
        dp[t]       = sp[t]       + ((t >= o)       ? sp[t - o]       : 0);
        dp[t + 256] = sp[t + 256] + ((t + 256 >= o) ? sp[t + 256 - o] : 0);
        __syncthreads();
        int* tmp = sp; sp = dp; dp = tmp;
    }
    for (int i = t; i < NBIN; i += 256) {
        int base = sp[i] - bs->tot[i];    // exclusive
        binscan[i] = base;
        gcur[i] = base;
    }
    if (t == 0) binscan[NBIN] = NE;
}

__device__ __forceinline__ void scatter_body(int bb, const int* __restrict__ src,
                                             const int* __restrict__ dst,
                                             const int* __restrict__ h,
                                             int* __restrict__ gcur,
                                             int* __restrict__ ebuf, int* cur) {
    const int t = threadIdx.x;
    for (int i = t; i < NBIN; i += 256) {
        int c = h[i * HB + bb];
        cur[i] = c ? atomicAdd(&gcur[i], c) : 0;
    }
    __syncthreads();
    const int base = bb * EPB;
#pragma unroll
    for (int i = 0; i < EPB / 256; ++i) {
        int e = base + i * 256 + t;
        if (e < NE) {
            int s = src[e], d = dst[e];
            int pos = atomicAdd(&cur[d >> 7], 1);
            ebuf[pos] = s | ((d & 127) << 16);
        }
    }
}

__device__ __forceinline__ void rank_body(int bin, const int* __restrict__ ebuf,
                                          const int* __restrict__ binscan,
                                          int* __restrict__ off,
                                          float* __restrict__ dis,
                                          unsigned short* __restrict__ rec,
                                          RKMem* rk) {
    const int t = threadIdx.x;
    const int base = binscan[bin];
    const int end  = binscan[bin + 1];
    if (t < 128) rk->cnt[t] = 0;
    __syncthreads();
    for (int e = base + t; e < end; e += 256)
        atomicAdd(&rk->cnt[(ebuf[e] >> 16) & 127], 1);
    __syncthreads();
    int c = (t < 128) ? rk->cnt[t] : 0;
    rk->s[t] = c;
    __syncthreads();
    for (int o = 1; o < 256; o <<= 1) {
        int x = (t >= o) ? rk->s[t - o] : 0;
        __syncthreads();
        rk->s[t] += x;
        __syncthreads();
    }
    int lo = rk->s[t] - c;                     // exclusive within bucket
    int d = (bin << 7) + t;
    if (t < 128 && d < NN) {
        off[d] = base + lo;
        dis[d] = rsqrtf((float)(c + 1));       // +1 self-loop
    }
    if (bin == NBIN - 1 && t == 0) off[NN] = NE;
    if (t < 128) rk->cur[t] = base + lo;
    __syncthreads();
    for (int e = base + t; e < end; e += 256) {
        int ed = ebuf[e];
        int p = atomicAdd(&rk->cur[(ed >> 16) & 127], 1);
        rec[p] = (unsigned short)(ed & 0xFFFF);
    }
}

__device__ __forceinline__ void agg1g2_body(int n, const unsigned char* __restrict__ H1,
                                            const float* __restrict__ dis,
                                            const float* __restrict__ b1,
                                            const __bf16* __restrict__ W2T,
                                            const int* __restrict__ off,
                                            const unsigned short* __restrict__ rec,
                                            __bf16* __restrict__ H2) {
    const int lane = threadIdx.x & 63;
    const int g = lane >> 4, l16 = lane & 15;
    const int fo = l16 * 8;
    const float dn = dis[n];

    float a[8];
#pragma unroll
    for (int i = 0; i < 8; ++i) a[i] = 0.f;

    const int e0 = off[n], e1 = off[n + 1];
    int e = e0 + g;
    for (; e + 12 < e1; e += 16) {
        int r0 = rec[e];
        int r1 = rec[e + 4];
        int r2 = rec[e + 8];
        int r3 = rec[e + 12];
        float w0 = dis[r0], w1 = dis[r1], w2 = dis[r2], w3 = dis[r3];
        uint2 u0 = *(const uint2*)&H1[(size_t)r0 * DF + fo];
        uint2 u1 = *(const uint2*)&H1[(size_t)r1 * DF + fo];
        uint2 u2 = *(const uint2*)&H1[(size_t)r2 * DF + fo];
        uint2 u3 = *(const uint2*)&H1[(size_t)r3 * DF + fo];
#define ACC8(u, w)                                                        \
        {                                                                 \
            f32x2 p0 = __builtin_amdgcn_cvt_pk_f32_fp8((u).x, false);     \
            f32x2 p1 = __builtin_amdgcn_cvt_pk_f32_fp8((u).x, true);      \
            f32x2 p2 = __builtin_amdgcn_cvt_pk_f32_fp8((u).y, false);     \
            f32x2 p3 = __builtin_amdgcn_cvt_pk_f32_fp8((u).y, true);      \
            a[0] += p0[0] * (w); a[1] += p0[1] * (w);                     \
            a[2] += p1[0] * (w); a[3] += p1[1] * (w);                     \
            a[4] += p2[0] * (w); a[5] += p2[1] * (w);                     \
            a[6] += p3[0] * (w); a[7] += p3[1] * (w);                     \
        }
        ACC8(u0, w0) ACC8(u1, w1) ACC8(u2, w2) ACC8(u3, w3)
    }
    for (; e < e1; e += 4) {
        int r = rec[e];
        float w = dis[r];
        uint2 u = *(const uint2*)&H1[(size_t)r * DF + fo];
        ACC8(u, w)
    }
#undef ACC8
#pragma unroll
    for (int i = 0; i < 8; ++i) {
        a[i] += __shfl_xor(a[i], 16);
        a[i] += __shfl_xor(a[i], 32);
    }
    {
        const float d2 = dn * dn;
        float4 b0 = *(const float4*)&b1[fo];
        float4 b4 = *(const float4*)&b1[fo + 4];
        uint2 us = *(const uint2*)&H1[(size_t)n * DF + fo];
        f32x2 s0 = __builtin_amdgcn_cvt_pk_f32_fp8(us.x, false);
        f32x2 s1 = __builtin_amdgcn_cvt_pk_f32_fp8(us.x, true);
        f32x2 s2 = __builtin_amdgcn_cvt_pk_f32_fp8(us.y, false);
        f32x2 s3 = __builtin_amdgcn_cvt_pk_f32_fp8(us.y, true);
        a[0] = fmaxf(a[0] * dn + s0[0] * d2 + b0.x, 0.f);
        a[1] = fmaxf(a[1] * dn + s0[1] * d2 + b0.y, 0.f);
        a[2] = fmaxf(a[2] * dn + s1[0] * d2 + b0.z, 0.f);
        a[3] = fmaxf(a[3] * dn + s1[1] * d2 + b0.w, 0.f);
        a[4] = fmaxf(a[4] * dn + s2[0] * d2 + b4.x, 0.f);
        a[5] = fmaxf(a[5] * dn + s2[1] * d2 + b4.y, 0.f);
        a[6] = fmaxf(a[6] * dn + s3[0] * d2 + b4.z, 0.f);
        a[7] = fmaxf(a[7] * dn + s3[1] * d2 + b4.w, 0.f);
    }
    float p[4];
#pragma unroll
    for (int j = 0; j < 4; ++j) {
        bf16x8 wr = *(const bf16x8*)&W2T[(size_t)(g * 4 + j) * DF + fo];
        float s = 0.f;
#pragma unroll
        for (int i = 0; i < 8; ++i) s += a[i] * (float)wr[i];
        p[j] = s;
    }
#pragma unroll
    for (int o = 1; o <= 8; o <<= 1) {
#pragma unroll
        for (int j = 0; j < 4; ++j) p[j] += __shfl_xor(p[j], o);
    }
    if (l16 == 0) {
        bf16x4 o4;
        o4[0] = (__bf16)p[0]; o4[1] = (__bf16)p[1];
        o4[2] = (__bf16)p[2]; o4[3] = (__bf16)p[3];
        *(bf16x4*)&H2[(size_t)n * NC + g * 4] = o4;
    }
}

__device__ __forceinline__ void agg2_body(int n, const __bf16* __restrict__ H2,
                                          const float* __restrict__ dis,
                                          const float* __restrict__ b2,
                                          const int* __restrict__ off,
                                          const unsigned short* __restrict__ rec,
                                          float* __restrict__ OUT) {
    const int lane = threadIdx.x & 63;
    const float dn = dis[n];
    const int g = lane >> 3, l8 = lane & 7;
    float ax = 0.f, ay = 0.f;
    const int e0 = off[n], e1 = off[n + 1];
    int e = e0 + g;
    for (; e + 8 < e1; e += 16) {
        int r0 = rec[e];
        int r1 = rec[e + 8];
        float w0 = dis[r0], w1 = dis[r1];
        bf16x2 h0 = *(const bf16x2*)&H2[(size_t)r0 * NC + l8 * 2];
        bf16x2 h1 = *(const bf16x2*)&H2[(size_t)r1 * NC + l8 * 2];
        ax += (float)h0[0] * w0;
        ay += (float)h0[1] * w0;
        ax += (float)h1[0] * w1;
        ay += (float)h1[1] * w1;
    }
    for (; e < e1; e += 8) {
        int r = rec[e];
        float w = dis[r];
        bf16x2 hh = *(const bf16x2*)&H2[(size_t)r * NC + l8 * 2];
        ax += (float)hh[0] * w;
        ay += (float)hh[1] * w;
    }
    ax += __shfl_xor(ax, 8);  ay += __shfl_xor(ay, 8);
    ax += __shfl_xor(ax, 16); ay += __shfl_xor(ay, 16);
    ax += __shfl_xor(ax, 32); ay += __shfl_xor(ay, 32);
    if (g == 0) {
        float d2 = dn * dn;
        bf16x2 hs = *(const bf16x2*)&H2[(size_t)n * NC + l8 * 2];
        float2 bb = *(const float2*)&b2[l8 * 2];
        float vx = ax * dn + (float)hs[0] * d2 + bb.x;
        float vy = ay * dn + (float)hs[1] * d2 + bb.y;
        float2 o = { 1.0f / (1.0f + expf(-vx)), 1.0f / (1.0f + expf(-vy)) };
        *(float2*)&OUT[(size_t)n * NC + l8 * 2] = o;
    }
}

// ================= cooperative mega-kernel =================
__global__ __launch_bounds__(256, 4) void k_mega(const float* __restrict__ X,
                                                 const int* __restrict__ EI,
                                                 const float* __restrict__ W1,
                                                 const float* __restrict__ b1,
                                                 const float* __restrict__ W2,
                                                 const float* __restrict__ b2,
                                                 float* __restrict__ OUT,
                                                 char* wsb) {
    __shared__ MegaSMem sm;
    cg::grid_group grid = cg::this_grid();
    const int NG = gridDim.x;

    const int* src = EI;
    const int* dst = EI + NE;
    int*    h       = (int*)(wsb);
    int*    binscan = (int*)(wsb + 163840);
    int*    gcur    = (int*)(wsb + 167936);
    int*    off     = (int*)(wsb + 172032);
    float*  dis     = (float*)(wsb + 376832);
    __bf16* W2T     = (__bf16*)(wsb + 581632);
    int*    ebuf    = (int*)(wsb + 589824);
    unsigned short* rec = (unsigned short*)(wsb + 3789824);
    unsigned char*  H1  = (unsigned char*)(wsb + 5389824);
    __bf16* H2      = (__bf16*)(wsb + 11789824);

    // P1: gemm1 | hist
    for (int vb = blockIdx.x; vb < GB + HB; vb += NG) {
        if (vb < GB) gemm1_body(vb, X, W1, H1, sm.wlds);
        else         hist_body(vb - GB, dst, h, sm.cur);
        __syncthreads();
    }
    grid.sync();
    // P2: bin scan + W2T (block 0)
    if (blockIdx.x == 0) binscan_body(h, binscan, gcur, W2, W2T, &sm.bs);
    grid.sync();
    // P3: scatter
    for (int vb = blockIdx.x; vb < HB; vb += NG) {
        scatter_body(vb, src, dst, h, gcur, ebuf, sm.cur);
        __syncthreads();
    }
    grid.sync();
    // P4: rank
    for (int vb = blockIdx.x; vb < NBIN; vb += NG) {
        rank_body(vb, ebuf, binscan, off, dis, rec, &sm.rk);
        __syncthreads();
    }
    grid.sync();
    // P5: agg1 + mini-GEMM2
    for (int vb = blockIdx.x; vb < NAGG; vb += NG) {
        int n = vb * 4 + (threadIdx.x >> 6);
        if (n < NN) agg1g2_body(n, H1, dis, b1, W2T, off, rec, H2);
    }
    grid.sync();
    // P6: agg2 + sigmoid
    for (int vb = blockIdx.x; vb < NAGG; vb += NG) {
        int n = vb * 4 + (threadIdx.x >> 6);
        if (n < NN) agg2_body(n, H2, dis, b2, off, rec, OUT);
    }
}

// ================= fallback pipeline kernels =================
__global__ __launch_bounds__(256) void k_hist_s(const int* __restrict__ dst,
                                                int* __restrict__ h) {
    __shared__ int cur[NBIN];
    hist_body(blockIdx.x, dst, h, cur);
}

__global__ __launch_bounds__(256) void k_binscan_s(const int* __restrict__ h,
                                                   int* __restrict__ binscan,
                                                   int* __restrict__ gcur,
                                                   const float* __restrict__ W2,
                                                   __bf16* __restrict__ W2T) {
    __shared__ BSMem bs;
    binscan_body(h, binscan, gcur, W2, W2T, &bs);
}

__global__ __launch_bounds__(256) void k_g1s_s(const float* __restrict__ X,
                                               const float* __restrict__ W1,
                                               unsigned char* __restrict__ H1,
                                               const int* __restrict__ src,
                                               const int* __restrict__ dst,
                                               const int* __restrict__ h,
                                               int* __restrict__ gcur,
                                               int* __restrict__ ebuf) {
    __shared__ MegaSMem sm;
    if (blockIdx.x < GB) gemm1_body(blockIdx.x, X, W1, H1, sm.wlds);
    else                 scatter_body(blockIdx.x - GB, src, dst, h, gcur, ebuf, sm.cur);
}

__global__ __launch_bounds__(256) void k_rank_s(const int* __restrict__ ebuf,
                                                const int* __restrict__ binscan,
                                                int* __restrict__ off,
                                                float* __restrict__ dis,
                                                unsigned short* __restrict__ rec) {
    __shared__ RKMem rk;
    rank_body(blockIdx.x, ebuf, binscan, off, dis, rec, &rk);
}

__global__ __launch_bounds__(256) void k_agg1g2_s(const unsigned char* __restrict__ H1,
                                                  const float* __restrict__ dis,
                                                  const float* __restrict__ b1,
                                                  const __bf16* __restrict__ W2T,
                                                  const int* __restrict__ off,
                                                  const unsigned short* __restrict__ rec,
                                                  __bf16* __restrict__ H2) {
    int n = blockIdx.x * 4 + (threadIdx.x >> 6);
    if (n < NN) agg1g2_body(n, H1, dis, b1, W2T, off, rec, H2);
}

__global__ __launch_bounds__(256) void k_agg2_s(const __bf16* __restrict__ H2,
                                                const float* __restrict__ dis,
                                                const float* __restrict__ b2,
                                                const int* __restrict__ off,
                                                const unsigned short* __restrict__ rec,
                                                float* __restrict__ OUT) {
    int n = blockIdx.x * 4 + (threadIdx.x >> 6);
    if (n < NN) agg2_body(n, H2, dis, b2, off, rec, OUT);
}

extern "C" void kernel_launch(void* const* d_in, const int* in_sizes, int n_in,
                              void* d_out, int out_size, void* d_ws, size_t ws_size,
                              hipStream_t stream) {
    const float* X  = (const float*)d_in[0];
    const int*   EI = (const int*)d_in[1];
    const float* W1 = (const float*)d_in[2];
    const float* b1 = (const float*)d_in[3];
    const float* W2 = (const float*)d_in[4];
    const float* b2 = (const float*)d_in[5];
    float* OUT = (float*)d_out;
    char*  wsb = (char*)d_ws;

    const int* src = EI;
    const int* dst = EI + NE;
    int*    h       = (int*)(wsb);
    int*    binscan = (int*)(wsb + 163840);
    int*    gcur    = (int*)(wsb + 167936);
    int*    off     = (int*)(wsb + 172032);
    float*  dis     = (float*)(wsb + 376832);
    __bf16* W2T     = (__bf16*)(wsb + 581632);
    int*    ebuf    = (int*)(wsb + 589824);
    unsigned short* rec = (unsigned short*)(wsb + 3789824);
    unsigned char*  H1  = (unsigned char*)(wsb + 5389824);
    __bf16* H2      = (__bf16*)(wsb + 11789824);

    // cooperative path: query real co-residency, launch with exactly that grid
    hipError_t err = hipErrorUnknown;
    int mb = 0;
    hipError_t oe = hipOccupancyMaxActiveBlocksPerMultiprocessor(
        &mb, (const void*)k_mega, 256, 0);
    if (oe == hipSuccess && mb >= 1) {
        int dev = 0, cus = 0;
        hipGetDevice(&dev);
        if (hipDeviceGetAttribute(&cus, hipDeviceAttributeMultiprocessorCount, dev)
                != hipSuccess || cus <= 0)
            cus = 256;
        int ngrid = mb * cus;
        if (ngrid > 8192) ngrid = 8192;
        void* args[] = { (void*)&X, (void*)&EI, (void*)&W1, (void*)&b1,
                         (void*)&W2, (void*)&b2, (void*)&OUT, (void*)&wsb };
        err = hipLaunchCooperativeKernel((void*)k_mega, dim3(ngrid), dim3(256),
                                         args, 0, stream);
    }
    if (err != hipSuccess) {
        // fallback: equivalent 6-launch pipeline (identical output)
        const int B = 256;
        k_hist_s<<<HB, B, 0, stream>>>(dst, h);
        k_binscan_s<<<1, B, 0, stream>>>(h, binscan, gcur, W2, W2T);
        k_g1s_s<<<GB + HB, B, 0, stream>>>(X, W1, H1, src, dst, h, gcur, ebuf);
        k_rank_s<<<NBIN, B, 0, stream>>>(ebuf, binscan, off, dis, rec);
        k_agg1g2_s<<<NAGG, B, 0, stream>>>(H1, dis, b1, W2T, off, rec, H2);
        k_agg2_s<<<NAGG, B, 0, stream>>>(H2, dis, b2, off, rec, OUT);
    }
}

// Round 19
// 103.931 us; speedup vs baseline: 4.6295x; 4.6295x over previous
//
#include <hip/hip_runtime.h>
#include <math.h>

#define NN 50000
#define NE 800000
#define DF 128
#define NC 16
#define WLD 136            // padded LDS row stride (bf16 elems)
#define NBIN 391           // buckets: bin = dst>>7 (128 nodes per bucket)
#define EPB 8192           // edges per hist/scatter block
#define HB ((NE + EPB - 1) / EPB)      // 98 hist/scatter blocks
#define HL (NBIN * HB)                 // 38318 h entries
#define PB ((HL + 255) / 256)          // 150 scan blocks
#define GB ((NN + 63) / 64)            // 782 gemm1 blocks

typedef __bf16 bf16x8 __attribute__((ext_vector_type(8)));
typedef __bf16 bf16x4 __attribute__((ext_vector_type(4)));
typedef __bf16 bf16x2 __attribute__((ext_vector_type(2)));
typedef float  f32x4  __attribute__((ext_vector_type(4)));
typedef float  f32x2  __attribute__((ext_vector_type(2)));

// ---------------- histogram of dst>>7 per edge block ----------------
__global__ __launch_bounds__(256) void k_hist(const int* __restrict__ dst,
                                              int* __restrict__ h) {
    __shared__ int hc[NBIN];
    const int bb = blockIdx.x, t = threadIdx.x;
    for (int i = t; i < NBIN; i += 256) hc[i] = 0;
    __syncthreads();
    const int base = bb * EPB;
#pragma unroll
    for (int i = 0; i < EPB / 256; ++i) {
        int e = base + i * 256 + t;
        if (e < NE) atomicAdd(&hc[dst[e] >> 7], 1);
    }
    __syncthreads();
    for (int i = t; i < NBIN; i += 256) h[i * HB + bb] = hc[i];   // bin-major
}

// ---------------- scan phase 1: per-block partial sums of h ----------------
__global__ __launch_bounds__(256) void k_hpart(const int* __restrict__ h,
                                               int* __restrict__ part) {
    __shared__ int ws[4];
    const int b = blockIdx.x, t = threadIdx.x;
    const int idx = b * 256 + t;
    int s = (idx < HL) ? h[idx] : 0;
    for (int o = 32; o > 0; o >>= 1) s += __shfl_down(s, o);
    if ((t & 63) == 0) ws[t >> 6] = s;
    __syncthreads();
    if (t == 0) part[b] = ws[0] + ws[1] + ws[2] + ws[3];
}

// ---------------- scan phase 2: scan PB partials + W2->W2T conversion -------
__global__ __launch_bounds__(256) void k_hscan_part(const int* __restrict__ part,
                                                    int* __restrict__ partoff,
                                                    int* __restrict__ hscan,
                                                    const float* __restrict__ W2,
                                                    __bf16* __restrict__ W2T) {
    __shared__ int s[256];
    const int t = threadIdx.x;
    // fused W2T conversion (block is otherwise mostly idle)
    for (int i = t; i < NC * DF; i += 256) {
        int n = i >> 7, k = i & 127;
        W2T[i] = (__bf16)W2[k * NC + n];
    }
    int v = (t < PB) ? part[t] : 0;
    s[t] = v;
    __syncthreads();
    for (int o = 1; o < 256; o <<= 1) {
        int x = (t >= o) ? s[t - o] : 0;
        __syncthreads();
        s[t] += x;
        __syncthreads();
    }
    if (t < PB) partoff[t] = s[t] - v;       // exclusive
    if (t == 255) hscan[HL] = s[255];        // sentinel = NE
}

// ---------------- scan phase 3: block-local scan -> hscan -------------------
__global__ __launch_bounds__(256) void k_hoff(const int* __restrict__ h,
                                              const int* __restrict__ partoff,
                                              int* __restrict__ hscan) {
    __shared__ int s[256];
    const int b = blockIdx.x, t = threadIdx.x;
    const int idx = b * 256 + t;
    int v = (idx < HL) ? h[idx] : 0;
    s[t] = v;
    __syncthreads();
    for (int o = 1; o < 256; o <<= 1) {
        int x = (t >= o) ? s[t - o] : 0;
        __syncthreads();
        s[t] += x;
        __syncthreads();
    }
    if (idx < HL) hscan[idx] = partoff[b] + s[t] - v;
}

// ---------------- fused: [0,GB) gemm1 (MFMA, W1 f32 -> LDS bf16, fp8 out) |
// ----------------        [GB,GB+HB) scatter into buckets (LDS cursors) ------
__global__ __launch_bounds__(256) void k_gemm1_scatter(const float* __restrict__ X,
                                                       const float* __restrict__ W1,
                                                       unsigned char* __restrict__ H1,
                                                       const int* __restrict__ src,
                                                       const int* __restrict__ dst,
                                                       const int* __restrict__ hscan,
                                                       int* __restrict__ ebuf) {
    __shared__ __bf16 wlds[DF * WLD];   // 34 KB
    __shared__ int cur[NBIN];
    if (blockIdx.x >= GB) {
        const int bb = blockIdx.x - GB;
        const int t = threadIdx.x;
        for (int i = t; i < NBIN; i += 256) cur[i] = hscan[i * HB + bb];
        __syncthreads();
        const int base = bb * EPB;
#pragma unroll
        for (int i = 0; i < EPB / 256; ++i) {
            int e = base + i * 256 + t;
            if (e < NE) {
                int s = src[e], d = dst[e];
                int pos = atomicAdd(&cur[d >> 7], 1);
                ebuf[pos] = s | ((d & 127) << 16);
            }
        }
        return;
    }
    const int wid = threadIdx.x >> 6, lane = threadIdx.x & 63;
    const int m0 = blockIdx.x * 64 + wid * 16;
    const int m = m0 + (lane & 15);
    const int mc = (m < NN) ? m : NN - 1;
    const int l15 = lane & 15;
    const int kb = (lane >> 4) * 8;

    // prefetch all 8 X float4 chunks (independent, in flight together)
    float4 xf[8];
#pragma unroll
    for (int q = 0; q < 4; ++q) {
        xf[2 * q]     = *(const float4*)&X[(size_t)mc * DF + q * 32 + kb];
        xf[2 * q + 1] = *(const float4*)&X[(size_t)mc * DF + q * 32 + kb + 4];
    }
    // transpose W1 (f32, [k][n]) -> wlds[n][k] bf16 (one-time staging)
    for (int i = threadIdx.x; i < DF * DF; i += 256) {
        int k = i >> 7, n = i & 127;
        wlds[n * WLD + k] = (__bf16)W1[i];
    }
    __syncthreads();

    f32x4 acc[8];
#pragma unroll
    for (int nf = 0; nf < 8; ++nf) acc[nf] = (f32x4){0.f, 0.f, 0.f, 0.f};
#pragma unroll
    for (int ks = 0; ks < 4; ++ks) {
        float4 x0 = xf[2 * ks], x1 = xf[2 * ks + 1];
        bf16x8 xa;
        xa[0] = (__bf16)x0.x; xa[1] = (__bf16)x0.y; xa[2] = (__bf16)x0.z; xa[3] = (__bf16)x0.w;
        xa[4] = (__bf16)x1.x; xa[5] = (__bf16)x1.y; xa[6] = (__bf16)x1.z; xa[7] = (__bf16)x1.w;
#pragma unroll
        for (int nf = 0; nf < 8; ++nf) {
            bf16x8 wa = *(const bf16x8*)&wlds[(nf * 16 + l15) * WLD + ks * 32 + kb];
            acc[nf] = __builtin_amdgcn_mfma_f32_16x16x32_bf16(wa, xa, acc[nf], 0, 0, 0);
        }
    }
    if (m < NN) {
#pragma unroll
        for (int nf = 0; nf < 8; ++nf) {   // pack 4 f32 -> 4 fp8 e4m3 bytes
            int pw = __builtin_amdgcn_cvt_pk_fp8_f32(acc[nf][0], acc[nf][1], 0, false);
            pw = __builtin_amdgcn_cvt_pk_fp8_f32(acc[nf][2], acc[nf][3], pw, true);
            *(unsigned int*)&H1[(size_t)m * DF + nf * 16 + (lane >> 4) * 4] = (unsigned int)pw;
        }
    }
}

// ---------------- per-bucket rank (128 nodes): off, dis, rec[src] -----------
__global__ __launch_bounds__(256) void k_rankB(const int* __restrict__ ebuf,
                                               const int* __restrict__ hscan,
                                               int* __restrict__ off,
                                               float* __restrict__ dis,
                                               unsigned short* __restrict__ rec) {
    __shared__ int cnt[128], s[256], cur[128];
    const int bin = blockIdx.x, t = threadIdx.x;
    const int base = hscan[bin * HB];
    const int end  = hscan[(bin + 1) * HB];   // bin+1==NBIN -> sentinel = NE
    if (t < 128) cnt[t] = 0;
    __syncthreads();
    for (int e = base + t; e < end; e += 256)
        atomicAdd(&cnt[(ebuf[e] >> 16) & 127], 1);
    __syncthreads();
    int c = (t < 128) ? cnt[t] : 0;
    s[t] = c;
    __syncthreads();
    for (int o = 1; o < 256; o <<= 1) {
        int x = (t >= o) ? s[t - o] : 0;
        __syncthreads();
        s[t] += x;
        __syncthreads();
    }
    int lo = s[t] - c;                         // exclusive within bucket
    int d = (bin << 7) + t;
    if (t < 128 && d < NN) {
        off[d] = base + lo;
        dis[d] = rsqrtf((float)(c + 1));       // +1 self-loop
    }
    if (bin == NBIN - 1 && t == 0) off[NN] = NE;
    if (t < 128) cur[t] = base + lo;
    __syncthreads();
    for (int e = base + t; e < end; e += 256) {
        int ed = ebuf[e];
        int p = atomicAdd(&cur[(ed >> 16) & 127], 1);
        rec[p] = (unsigned short)(ed & 0xFFFF);
    }
}

// ---------------- agg1 + gemm2 fused: one node per wave, unroll-4, fp8 H1 ---
__global__ __launch_bounds__(256) void k_agg1g2(const unsigned char* __restrict__ H1,
                                                const float* __restrict__ dis,
                                                const float* __restrict__ b1,
                                                const __bf16* __restrict__ W2T,
                                                const int* __restrict__ off,
                                                const unsigned short* __restrict__ rec,
                                                __bf16* __restrict__ H2) {
    const int wid = threadIdx.x >> 6, lane = threadIdx.x & 63;
    const int n = blockIdx.x * 4 + wid;
    if (n >= NN) return;
    const int g = lane >> 4, l16 = lane & 15;
    const int fo = l16 * 8;                    // feat (and byte) offset
    const float dn = dis[n];

    float a[8];
#pragma unroll
    for (int i = 0; i < 8; ++i) a[i] = 0.f;

    const int e0 = off[n], e1 = off[n + 1];
    int e = e0 + g;
    // 4 edges in flight per 16-lane group (16 rows in flight per wave)
    for (; e + 12 < e1; e += 16) {
        int r0 = rec[e];
        int r1 = rec[e + 4];
        int r2 = rec[e + 8];
        int r3 = rec[e + 12];
        float w0 = dis[r0], w1 = dis[r1], w2 = dis[r2], w3 = dis[r3];
        uint2 u0 = *(const uint2*)&H1[(size_t)r0 * DF + fo];
        uint2 u1 = *(const uint2*)&H1[(size_t)r1 * DF + fo];
        uint2 u2 = *(const uint2*)&H1[(size_t)r2 * DF + fo];
        uint2 u3 = *(const uint2*)&H1[(size_t)r3 * DF + fo];
#define ACC8(u, w)                                                        \
        {                                                                 \
            f32x2 p0 = __builtin_amdgcn_cvt_pk_f32_fp8((u).x, false);     \
            f32x2 p1 = __builtin_amdgcn_cvt_pk_f32_fp8((u).x, true);      \
            f32x2 p2 = __builtin_amdgcn_cvt_pk_f32_fp8((u).y, false);     \
            f32x2 p3 = __builtin_amdgcn_cvt_pk_f32_fp8((u).y, true);      \
            a[0] += p0[0] * (w); a[1] += p0[1] * (w);                     \
            a[2] += p1[0] * (w); a[3] += p1[1] * (w);                     \
            a[4] += p2[0] * (w); a[5] += p2[1] * (w);                     \
            a[6] += p3[0] * (w); a[7] += p3[1] * (w);                     \
        }
        ACC8(u0, w0) ACC8(u1, w1) ACC8(u2, w2) ACC8(u3, w3)
    }
    for (; e < e1; e += 4) {
        int r = rec[e];
        float w = dis[r];
        uint2 u = *(const uint2*)&H1[(size_t)r * DF + fo];
        ACC8(u, w)
    }
#undef ACC8
#pragma unroll
    for (int i = 0; i < 8; ++i) {
        a[i] += __shfl_xor(a[i], 16);
        a[i] += __shfl_xor(a[i], 32);
    }
    // finalize on ALL lanes: a = relu(edge_sum*dn + self*dn^2 + bias)
    {
        const float d2 = dn * dn;
        float4 b0 = *(const float4*)&b1[fo];
        float4 b4 = *(const float4*)&b1[fo + 4];
        uint2 us = *(const uint2*)&H1[(size_t)n * DF + fo];
        f32x2 s0 = __builtin_amdgcn_cvt_pk_f32_fp8(us.x, false);
        f32x2 s1 = __builtin_amdgcn_cvt_pk_f32_fp8(us.x, true);
        f32x2 s2 = __builtin_amdgcn_cvt_pk_f32_fp8(us.y, false);
        f32x2 s3 = __builtin_amdgcn_cvt_pk_f32_fp8(us.y, true);
        a[0] = fmaxf(a[0] * dn + s0[0] * d2 + b0.x, 0.f);
        a[1] = fmaxf(a[1] * dn + s0[1] * d2 + b0.y, 0.f);
        a[2] = fmaxf(a[2] * dn + s1[0] * d2 + b0.z, 0.f);
        a[3] = fmaxf(a[3] * dn + s1[1] * d2 + b0.w, 0.f);
        a[4] = fmaxf(a[4] * dn + s2[0] * d2 + b4.x, 0.f);
        a[5] = fmaxf(a[5] * dn + s2[1] * d2 + b4.y, 0.f);
        a[6] = fmaxf(a[6] * dn + s3[0] * d2 + b4.z, 0.f);
        a[7] = fmaxf(a[7] * dn + s3[1] * d2 + b4.w, 0.f);
    }

    // mini-GEMM: lane computes 4 classes (g*4..g*4+3) over its 8 feats
    float p[4];
#pragma unroll
    for (int j = 0; j < 4; ++j) {
        bf16x8 wr = *(const bf16x8*)&W2T[(size_t)(g * 4 + j) * DF + fo];
        float s = 0.f;
#pragma unroll
        for (int i = 0; i < 8; ++i) s += a[i] * (float)wr[i];
        p[j] = s;
    }
#pragma unroll
    for (int o = 1; o <= 8; o <<= 1) {
#pragma unroll
        for (int j = 0; j < 4; ++j) p[j] += __shfl_xor(p[j], o);
    }
    if (l16 == 0) {
        bf16x4 o4;
        o4[0] = (__bf16)p[0]; o4[1] = (__bf16)p[1];
        o4[2] = (__bf16)p[2]; o4[3] = (__bf16)p[3];
        *(bf16x4*)&H2[(size_t)n * NC + g * 4] = o4;
    }
}

// ---------------- agg layer 2: unroll-2, bf16 H2, fused sigmoid -> OUT ------
__global__ __launch_bounds__(256) void k_agg2(const __bf16* __restrict__ H2,
                                              const float* __restrict__ dis,
                                              const float* __restrict__ b2,
                                              const int* __restrict__ off,
                                              const unsigned short* __restrict__ rec,
                                              float* __restrict__ OUT) {
    const int wid = threadIdx.x >> 6, lane = threadIdx.x & 63;
    const int n = blockIdx.x * 4 + wid;
    if (n >= NN) return;
    const float dn = dis[n];

    const int g = lane >> 3, l8 = lane & 7;
    float ax = 0.f, ay = 0.f;
    const int e0 = off[n], e1 = off[n + 1];
    int e = e0 + g;
    for (; e + 8 < e1; e += 16) {
        int r0 = rec[e];
        int r1 = rec[e + 8];
        float w0 = dis[r0], w1 = dis[r1];
        bf16x2 h0 = *(const bf16x2*)&H2[(size_t)r0 * NC + l8 * 2];
        bf16x2 h1 = *(const bf16x2*)&H2[(size_t)r1 * NC + l8 * 2];
        ax += (float)h0[0] * w0;
        ay += (float)h0[1] * w0;
        ax += (float)h1[0] * w1;
        ay += (float)h1[1] * w1;
    }
    for (; e < e1; e += 8) {
        int r = rec[e];
        float w = dis[r];
        bf16x2 h = *(const bf16x2*)&H2[(size_t)r * NC + l8 * 2];
        ax += (float)h[0] * w;
        ay += (float)h[1] * w;
    }
    ax += __shfl_xor(ax, 8);  ay += __shfl_xor(ay, 8);
    ax += __shfl_xor(ax, 16); ay += __shfl_xor(ay, 16);
    ax += __shfl_xor(ax, 32); ay += __shfl_xor(ay, 32);
    if (g == 0) {
        float d2 = dn * dn;
        bf16x2 hs = *(const bf16x2*)&H2[(size_t)n * NC + l8 * 2];
        float2 bb = *(const float2*)&b2[l8 * 2];
        float vx = ax * dn + (float)hs[0] * d2 + bb.x;
        float vy = ay * dn + (float)hs[1] * d2 + bb.y;
        float2 o = { 1.0f / (1.0f + expf(-vx)), 1.0f / (1.0f + expf(-vy)) };
        *(float2*)&OUT[(size_t)n * NC + l8 * 2] = o;
    }
}

extern "C" void kernel_launch(void* const* d_in, const int* in_sizes, int n_in,
                              void* d_out, int out_size, void* d_ws, size_t ws_size,
                              hipStream_t stream) {
    const float* X  = (const float*)d_in[0];
    const int*   EI = (const int*)d_in[1];
    const float* W1 = (const float*)d_in[2];
    const float* b1 = (const float*)d_in[3];
    const float* W2 = (const float*)d_in[4];
    const float* b2 = (const float*)d_in[5];
    float* OUT = (float*)d_out;

    const int* src = EI;
    const int* dst = EI + NE;

    // workspace layout (bytes)
    char* ws = (char*)d_ws;
    int*    h       = (int*)(ws);                   // HL ints = 153.3 KB
    int*    hscan   = (int*)(ws + 163840);          // HL+1 ints
    int*    hpart   = (int*)(ws + 327680);          // PB ints
    int*    hpartoff= (int*)(ws + 331776);          // PB ints
    int*    off     = (int*)(ws + 335872);          // NN+1 ints
    float*  dis     = (float*)(ws + 540672);        // NN floats
    __bf16* W2T     = (__bf16*)(ws + 745472);       // 4 KB
    int*    ebuf    = (int*)(ws + 749568);          // NE int = 3.2 MB
    unsigned short* rec = (unsigned short*)(ws + 3949568);  // NE ushort = 1.6 MB
    unsigned char* H1 = (unsigned char*)(ws + 5549568);     // NN*DF fp8 = 6.4 MB
    __bf16* H2      = (__bf16*)(ws + 11949568);     // NN*NC bf16 = 1.6 MB

    const int B = 256;

    k_hist<<<HB, B, 0, stream>>>(dst, h);
    k_hpart<<<PB, B, 0, stream>>>(h, hpart);
    k_hscan_part<<<1, B, 0, stream>>>(hpart, hpartoff, hscan, W2, W2T);
    k_hoff<<<PB, B, 0, stream>>>(h, hpartoff, hscan);
    k_gemm1_scatter<<<GB + HB, B, 0, stream>>>(X, W1, H1, src, dst, hscan, ebuf);
    k_rankB<<<NBIN, B, 0, stream>>>(ebuf, hscan, off, dis, rec);
    k_agg1g2<<<(NN + 3) / 4, B, 0, stream>>>(H1, dis, b1, W2T, off, rec, H2);
    k_agg2<<<(NN + 3) / 4, B, 0, stream>>>(H2, dis, b2, off, rec, OUT);
}